// Round 9
// baseline (389.850 us; speedup 1.0000x reference)
//
#include <hip/hip_runtime.h>
#include <hip/hip_bf16.h>

#define BF16 __hip_bfloat16

typedef short short8 __attribute__((ext_vector_type(8)));
typedef short short4v __attribute__((ext_vector_type(4)));
typedef float v4f __attribute__((ext_vector_type(4)));
typedef float f4 __attribute__((ext_vector_type(4)));

__device__ float g_bp[1152];          // fused MLP bias (W2*b1 + b2)
__device__ BF16  g_wm[1152 * 1152];   // merged MLP weight (W2*W1), bf16

__device__ __forceinline__ short f2bs(float f) {
    __hip_bfloat16 h = __float2bfloat16(f);
    return *(short*)&h;
}

__device__ __forceinline__ float bs2f(short s) {
    __hip_bfloat16 h = *(__hip_bfloat16*)&s;
    return __bfloat162float(h);
}

// async global->LDS 16B copy (LDS dest: wave-uniform base + lane*16B)
__device__ __forceinline__ void async_cp16(const BF16* g, BF16* l) {
    __builtin_amdgcn_global_load_lds(
        (const __attribute__((address_space(1))) void*)g,
        (__attribute__((address_space(3))) void*)l,
        16, 0, 0);
}

// m204 bijective XCD-chunked swizzle
__device__ __forceinline__ int xcd_chunk(int u, int nwg) {
    int xcd = u & 7, i = u >> 3;
    int q = nwg >> 3, r = nwg & 7;
    return (xcd < r ? xcd * (q + 1) : r * (q + 1) + (xcd - r) * q) + i;
}

// ---------------------------------------------------------------------------
// L1 prep (unchanged)
// ---------------------------------------------------------------------------
__global__ __launch_bounds__(256) void prep_kernel(
    const float* __restrict__ wq, const float* __restrict__ wk,
    const float* __restrict__ wv, const float* __restrict__ wo,
    const float* __restrict__ wfc1, const float* __restrict__ wfc2,
    const float* __restrict__ x,
    const float* __restrict__ bfc1, const float* __restrict__ bfc2,
    BF16* __restrict__ wbq, BF16* __restrict__ wbk,
    BF16* __restrict__ wbv, BF16* __restrict__ wbo,
    BF16* __restrict__ wbf1t, BF16* __restrict__ wbf2,
    BF16* __restrict__ xb)
{
    __shared__ float tile[64][65];
    const int bid = blockIdx.x;
    const int tid = threadIdx.x;

    if (bid < 16641) {
        const int i = bid * 256 + tid;
        constexpr int N_DD  = 331776;
        constexpr int N4    = 4 * N_DD;
        constexpr int N_F2  = 1253376;
        constexpr int E_F2  = N4 + N_F2;
        constexpr int N_X   = 1679616;
        constexpr int TOTAL = E_F2 + N_X;

        if (i < N4) {
            int seg = i / N_DD, j = i - seg * N_DD;
            const float* s = (seg == 0) ? wq : (seg == 1) ? wk : (seg == 2) ? wv : wo;
            BF16* d = (seg == 0) ? wbq : (seg == 1) ? wbk : (seg == 2) ? wbv : wbo;
            f4 v = ((const f4*)s)[j];
            short4v o = {f2bs(v.x), f2bs(v.y), f2bs(v.z), f2bs(v.w)};
            ((short4v*)d)[j] = o;
        } else if (i < E_F2) {
            int j = i - N4;
            int row = j / 1088;
            int c = (j - row * 1088) * 4;
            short4v o = {0, 0, 0, 0};
            if (c < 4304) {
                f4 v = *(const f4*)(wfc2 + (size_t)row * 4304 + c);
                o[0] = f2bs(v.x); o[1] = f2bs(v.y); o[2] = f2bs(v.z); o[3] = f2bs(v.w);
            }
            *(short4v*)(wbf2 + (size_t)row * 4352 + c) = o;
        } else if (i < TOTAL) {
            int j = i - E_F2;
            f4 v = ((const f4*)x)[j];
            short4v o = {f2bs(v.x), f2bs(v.y), f2bs(v.z), f2bs(v.w)};
            ((short4v*)xb)[j] = o;
        }
    } else if (bid < 17865) {
        const int b2 = bid - 16641;
        const int h0 = (b2 % 68) * 64;
        const int d0 = (b2 / 68) * 64;
#pragma unroll
        for (int i = 0; i < 4; ++i) {
            int lin = tid + i * 256;
            int r = lin >> 4, c4 = lin & 15;
            f4 v = {0.f, 0.f, 0.f, 0.f};
            if (h0 + r < 4304)
                v = *(const f4*)(wfc1 + (size_t)(h0 + r) * 1152 + d0 + c4 * 4);
            tile[r][c4 * 4 + 0] = v.x;
            tile[r][c4 * 4 + 1] = v.y;
            tile[r][c4 * 4 + 2] = v.z;
            tile[r][c4 * 4 + 3] = v.w;
        }
        __syncthreads();
#pragma unroll
        for (int i = 0; i < 2; ++i) {
            int lin = tid + i * 256;
            int dr = lin >> 3, h8 = lin & 7;
            short8 o;
#pragma unroll
            for (int e = 0; e < 8; ++e)
                o[e] = f2bs(tile[h8 * 8 + e][dr]);
            *(short8*)(wbf1t + (size_t)(d0 + dr) * 4352 + h0 + h8 * 8) = o;
        }
    } else {
        const int row = (bid - 17865) * 4 + (tid >> 6);
        const int lane = tid & 63;
        const float* wr = wfc2 + (size_t)row * 4304;
        float s = 0.f;
        for (int k = lane; k < 4304; k += 64) s += wr[k] * bfc1[k];
#pragma unroll
        for (int mm = 1; mm < 64; mm <<= 1) s += __shfl_xor(s, mm, 64);
        if (lane == 0) g_bp[row] = s + bfc2[row];
    }
}

// ---------------------------------------------------------------------------
// L2: weight-merge (128², 2-phase) || fused QKV (256², 8-phase) — unchanged
// ---------------------------------------------------------------------------
__global__ __launch_bounds__(512, 2) void qkv_wm8_kernel(
    const BF16* __restrict__ A,
    const BF16* __restrict__ Wqkv,
    const float* __restrict__ b0, const float* __restrict__ b1,
    const float* __restrict__ b2,
    BF16* __restrict__ C, size_t cstride, int M,
    const BF16* __restrict__ W2,
    const BF16* __restrict__ W1t)
{
    __shared__ __align__(16) BF16 smem[65536];   // 128 KiB
    const int bid  = blockIdx.x;
    const int tid  = threadIdx.x;
    const int lane = tid & 63;
    const int wave = tid >> 6;
    const int quad = lane >> 4;
    const int l16  = lane & 15;
    const v4f zf = {0.f, 0.f, 0.f, 0.f};

    int rr[2], sw[2], lo[2];
#pragma unroll
    for (int j = 0; j < 2; ++j) {
        int c = tid + j * 512;
        rr[j] = c >> 3;
        sw[j] = (((c & 7) - (c >> 3)) & 7) << 3;
        lo[j] = (c & ~63) * 8;
    }

    if (bid < 81) {
        BF16* Am = smem;
        BF16* Bm = smem + 8192;
        const int m0 = (bid % 9) * 128;
        const int n0 = (bid / 9) * 128;
        const int wm = (wave >> 1) * 32;
        const int wn = (wave & 1) * 64;

        v4f acc[2][4];
#pragma unroll
        for (int i = 0; i < 2; ++i)
#pragma unroll
            for (int j = 0; j < 4; ++j) acc[i][j] = zf;

        const BF16* gA[2]; const BF16* gB[2];
#pragma unroll
        for (int j = 0; j < 2; ++j) {
            gA[j] = W2 + (size_t)(m0 + rr[j]) * 4352 + sw[j];
            gB[j] = W1t + (size_t)(n0 + rr[j]) * 4352 + sw[j];
        }

        for (int kt = 0; kt < 68; ++kt) {
#pragma unroll
            for (int j = 0; j < 2; ++j) { async_cp16(gA[j], Am + lo[j]); gA[j] += 64; }
#pragma unroll
            for (int j = 0; j < 2; ++j) { async_cp16(gB[j], Bm + lo[j]); gB[j] += 64; }
            __syncthreads();
#pragma unroll
            for (int ks = 0; ks < 2; ++ks) {
                short8 af[2], bfg[4];
#pragma unroll
                for (int mt = 0; mt < 2; ++mt) {
                    int row = wm + mt * 16 + l16;
                    af[mt] = *(const short8*)(Am + row * 64 + ((((ks << 2) | quad) + row & 7) & 7) * 8);
                }
#pragma unroll
                for (int nt = 0; nt < 4; ++nt) {
                    int row = wn + nt * 16 + l16;
                    bfg[nt] = *(const short8*)(Bm + row * 64 + ((((ks << 2) | quad) + row & 7) & 7) * 8);
                }
#pragma unroll
                for (int mt = 0; mt < 2; ++mt)
#pragma unroll
                    for (int nt = 0; nt < 4; ++nt)
                        acc[mt][nt] = __builtin_amdgcn_mfma_f32_16x16x32_bf16(
                            af[mt], bfg[nt], acc[mt][nt], 0, 0, 0);
            }
            __syncthreads();
        }

#pragma unroll
        for (int mt = 0; mt < 2; ++mt)
#pragma unroll
            for (int nt = 0; nt < 4; ++nt)
#pragma unroll
                for (int r2 = 0; r2 < 4; ++r2) {
                    int row_l = wm + mt * 16 + quad * 4 + r2;
                    int col_l = wn + nt * 16 + l16;
                    smem[row_l * 128 + col_l] = __float2bfloat16(acc[mt][nt][r2]);
                }
        __syncthreads();
#pragma unroll
        for (int p = 0; p < 4; ++p) {
            int idx = p * 512 + tid;
            *(short8*)(g_wm + (size_t)(m0 + (idx >> 4)) * 1152 + n0 + (idx & 15) * 8) =
                *(const short8*)(smem + idx * 8);
        }
    } else {
        const int wg = xcd_chunk(bid - 81, 322);
        const int m0 = (wg / 14) * 256;
        const int n0 = (wg % 14) * 256;
        const int wr = wave >> 2;
        const int wc = wave & 3;
        BF16* As = smem;
        BF16* Bs = smem + 32768;

        v4f acc[8][4];
#pragma unroll
        for (int i = 0; i < 8; ++i)
#pragma unroll
            for (int j = 0; j < 4; ++j) acc[i][j] = zf;

        #define STAGE_A(dd, hh, tt)                                            \
            {                                                                  \
                _Pragma("unroll")                                              \
                for (int j = 0; j < 2; ++j)                                    \
                    async_cp16(A + (size_t)(m0 + (hh) * 128 + rr[j]) * 1152    \
                                 + (tt) * 64 + sw[j],                          \
                               As + (dd) * 16384 + (hh) * 8192 + lo[j]);       \
            }
        #define STAGE_B(dd, hh, tt)                                            \
            {                                                                  \
                _Pragma("unroll")                                              \
                for (int j = 0; j < 2; ++j)                                    \
                    async_cp16(Wqkv + (size_t)(n0 + (hh) * 128 + rr[j]) * 1152 \
                                 + (tt) * 64 + sw[j],                          \
                               Bs + (dd) * 16384 + (hh) * 8192 + lo[j]);       \
            }

        STAGE_B(0, 0, 0); STAGE_B(0, 1, 0);
        STAGE_A(0, 0, 0); STAGE_A(0, 1, 0);
        STAGE_B(1, 0, 1); STAGE_B(1, 1, 1);
        asm volatile("s_waitcnt vmcnt(4)" ::: "memory");
        __builtin_amdgcn_s_barrier();
        __builtin_amdgcn_sched_barrier(0);

        short8 bfr[4][2], afr[2][2];
#pragma unroll 2
        for (int it = 0; it < 18; ++it) {
            const int d = it & 1;
            const BF16* Ad = As + d * 16384;
            const BF16* Bd = Bs + d * 16384;
#pragma unroll
            for (int q = 0; q < 4; ++q) {
                if (q == 0) {
#pragma unroll
                    for (int nt = 0; nt < 4; ++nt) {
                        int R = wc * 64 + nt * 16 + l16;
#pragma unroll
                        for (int ks = 0; ks < 2; ++ks)
                            bfr[nt][ks] = *(const short8*)(
                                Bd + R * 64 + ((((ks << 2) | quad) + R & 7) & 7) * 8);
                    }
                }
#pragma unroll
                for (int mi = 0; mi < 2; ++mi) {
                    int R = wr * 128 + (q * 2 + mi) * 16 + l16;
#pragma unroll
                    for (int ks = 0; ks < 2; ++ks)
                        afr[mi][ks] = *(const short8*)(
                            Ad + R * 64 + ((((ks << 2) | quad) + R & 7) & 7) * 8);
                }
                if (q == 0) { if (it + 1 < 18) STAGE_A(d ^ 1, 0, it + 1); }
                if (q == 1) { if (it + 1 < 18) STAGE_A(d ^ 1, 1, it + 1); }
                if (q == 2) { if (it + 2 < 18) STAGE_B(d,     0, it + 2); }
                if (q == 3) { if (it + 2 < 18) STAGE_B(d,     1, it + 2); }

                __builtin_amdgcn_s_barrier();
                asm volatile("s_waitcnt lgkmcnt(0)" ::: "memory");
                __builtin_amdgcn_sched_barrier(0);
                __builtin_amdgcn_s_setprio(1);
#pragma unroll
                for (int ks = 0; ks < 2; ++ks)
#pragma unroll
                    for (int mi = 0; mi < 2; ++mi)
#pragma unroll
                        for (int nt = 0; nt < 4; ++nt)
                            acc[q * 2 + mi][nt] = __builtin_amdgcn_mfma_f32_16x16x32_bf16(
                                afr[mi][ks], bfr[nt][ks], acc[q * 2 + mi][nt], 0, 0, 0);
                __builtin_amdgcn_s_setprio(0);
                if (q == 3) {
                    if (it + 2 < 18)
                        asm volatile("s_waitcnt vmcnt(4)" ::: "memory");
                    else
                        asm volatile("s_waitcnt vmcnt(0)" ::: "memory");
                }
                __builtin_amdgcn_s_barrier();
            }
        }
        #undef STAGE_A
        #undef STAGE_B

        float bv[4];
#pragma unroll
        for (int nt = 0; nt < 4; ++nt) {
            int col_g = n0 + wc * 64 + nt * 16 + l16;
            int sel = (col_g >= 2304) ? 2 : (col_g >= 1152) ? 1 : 0;
            const float* bp = (sel == 0) ? b0 : (sel == 1) ? b1 : b2;
            bv[nt] = (col_g < 3456) ? bp[col_g - sel * 1152] : 0.f;
        }
#pragma unroll
        for (int mt = 0; mt < 8; ++mt)
#pragma unroll
            for (int nt = 0; nt < 4; ++nt)
#pragma unroll
                for (int r2 = 0; r2 < 4; ++r2) {
                    int row_l = wr * 128 + mt * 16 + quad * 4 + r2;
                    int col_l = wc * 64 + nt * 16 + l16;
                    smem[row_l * 256 + col_l] = __float2bfloat16(acc[mt][nt][r2] + bv[nt]);
                }
        __syncthreads();
#pragma unroll
        for (int p = 0; p < 16; ++p) {
            int idx = p * 512 + tid;
            int row = m0 + (idx >> 5);
            int col_g = n0 + (idx & 31) * 8;
            if (row < M && col_g < 3456) {
                int sel = (col_g >= 2304) ? 2 : (col_g >= 1152) ? 1 : 0;
                *(short8*)(C + (size_t)sel * cstride + (size_t)row * 1152
                           + col_g - sel * 1152) =
                    *(const short8*)(smem + idx * 8);
            }
        }
    }
}

// ---------------------------------------------------------------------------
// L3: V transpose + VT tail init (unchanged)
// ---------------------------------------------------------------------------
__global__ __launch_bounds__(256) void trans_kernel(
    const BF16* __restrict__ V, BF16* __restrict__ VT)
{
    __shared__ __align__(16) BF16 tl[64][128];
    const int bid = blockIdx.x, tid = threadIdx.x;
    const short8 zero8 = {0, 0, 0, 0, 0, 0, 0, 0};

    if (bid < 1152) {
        const int hg = bid / 12, kb = bid - hg * 12;
        const int b = hg / 12, hh = hg - b * 12;
        const BF16* src = V + (size_t)b * 839808 + (size_t)hh * 69984;
        BF16* dst = VT + (size_t)hg * 86016;
        const int kk0 = kb * 64;
#pragma unroll
        for (int i = 0; i < 3; ++i) {
            int c = tid + i * 256;
            int r = c / 12, cg = c - r * 12;
            short8 v = (kk0 + r < 729)
                ? *(const short8*)(src + (size_t)(kk0 + r) * 96 + cg * 8) : zero8;
            *(short8*)(&tl[r][(cg ^ ((r >> 3) & 7)) * 8]) = v;
        }
        __syncthreads();
#pragma unroll
        for (int i = 0; i < 3; ++i) {
            int wc = tid + i * 256;
            int hd = wc >> 3, o = wc & 7;
            int sp = (((hd >> 3) ^ o) << 3) + (hd & 7);
            short8 out;
#pragma unroll
            for (int j = 0; j < 8; ++j)
                out[j] = *(const short*)&tl[o * 8 + j][sp];
            *(short8*)(dst + (size_t)hd * 768 + kk0 + o * 8) = out;
        }
    } else {
        int c = (bid - 1152) * 256 + tid;
        int hg = c / 1536, rem = c - hg * 1536;
        int r = rem / 96, ock = rem - r * 96;
        int kk = ock * 8;
        short8 v = zero8;
        if (r == 0) {
            const short oneb = 0x3F80;
#pragma unroll
            for (int j = 0; j < 8; ++j) v[j] = (kk + j < 729) ? oneb : (short)0;
        }
        *(short8*)(VT + (size_t)hg * 86016 + (size_t)(96 + r) * 768 + kk) = v;
    }
}

// ---------------------------------------------------------------------------
// GEMM (TM x 128, XCD-chunked). TM=224 for WO/apply: ceil(5832/224)=27
// m-tiles x 9 n-tiles = 243 blocks <= 256 CUs -> ONE round (vs 4 serial
// rounds at TM=64), and ds_read:MFMA ratio 0.39 (vs 0.75). LDS = max of
// staging (TM+128)*64 and epilogue TM*128 elems.
// ---------------------------------------------------------------------------
template<int TM>
__global__ __launch_bounds__(256) void gemm_bt_t(
    const BF16* __restrict__ A, int lda,
    const BF16* __restrict__ W, int ldb,
    const float* __restrict__ bias, int nbias,
    BF16* __restrict__ C, int ldc,
    int M, int Kr, int nbn)
{
    constexpr int MT = TM / 32;
    constexpr int SME = ((TM + 128) * 64 > TM * 128) ? (TM + 128) * 64 : TM * 128;
    __shared__ __align__(16) BF16 smem[SME];
    BF16* As = smem;
    BF16* Bs = smem + TM * 64;

    const int tid  = threadIdx.x;
    const int lane = tid & 63;
    const int wave = tid >> 6;
    const int quad = lane >> 4;
    const int l16  = lane & 15;
    const int wm   = (wave >> 1) * (TM / 2);
    const int wn   = (wave & 1) * 64;
    const int wg   = xcd_chunk(blockIdx.x, gridDim.x);
    const int m0   = (wg / nbn) * TM;
    const int n0   = (wg % nbn) * 128;
    if (m0 >= M) return;

    const v4f zf = {0.f, 0.f, 0.f, 0.f};
    v4f acc[MT][4];
#pragma unroll
    for (int i = 0; i < MT; ++i)
#pragma unroll
        for (int j = 0; j < 4; ++j) acc[i][j] = zf;

    const BF16* gA[MT]; BF16* lA[MT];
#pragma unroll
    for (int i = 0; i < MT; ++i) {
        int c = tid + i * 256;
        gA[i] = A + (size_t)(m0 + (c >> 3)) * lda + ((((c & 7) - (c >> 3)) & 7) << 3);
        lA[i] = As + (c & ~63) * 8;
    }
    const BF16* gB[4]; BF16* lB[4];
#pragma unroll
    for (int i = 0; i < 4; ++i) {
        int c = tid + i * 256;
        gB[i] = W + (size_t)(n0 + (c >> 3)) * ldb + ((((c & 7) - (c >> 3)) & 7) << 3);
        lB[i] = Bs + (c & ~63) * 8;
    }

    const int nk = Kr >> 6;
    for (int kt = 0; kt < nk; ++kt) {
#pragma unroll
        for (int i = 0; i < MT; ++i) { async_cp16(gA[i], lA[i]); gA[i] += 64; }
#pragma unroll
        for (int i = 0; i < 4; ++i)  { async_cp16(gB[i], lB[i]); gB[i] += 64; }
        __syncthreads();

#pragma unroll
        for (int ks = 0; ks < 2; ++ks) {
            short8 af[MT], bfg[4];
#pragma unroll
            for (int mt = 0; mt < MT; ++mt) {
                int row = wm + mt * 16 + l16;
                af[mt] = *(const short8*)(As + row * 64 + ((((ks << 2) | quad) + row & 7) & 7) * 8);
            }
#pragma unroll
            for (int nt = 0; nt < 4; ++nt) {
                int row = wn + nt * 16 + l16;
                bfg[nt] = *(const short8*)(Bs + row * 64 + ((((ks << 2) | quad) + row & 7) & 7) * 8);
            }
#pragma unroll
            for (int mt = 0; mt < MT; ++mt)
#pragma unroll
                for (int nt = 0; nt < 4; ++nt)
                    acc[mt][nt] = __builtin_amdgcn_mfma_f32_16x16x32_bf16(
                        af[mt], bfg[nt], acc[mt][nt], 0, 0, 0);
        }
        __syncthreads();
    }

    float bv[4];
#pragma unroll
    for (int nt = 0; nt < 4; ++nt) {
        int col = n0 + wn + nt * 16 + l16;
        bv[nt] = (col < nbias) ? bias[col] : 0.f;
    }
#pragma unroll
    for (int mt = 0; mt < MT; ++mt)
#pragma unroll
        for (int nt = 0; nt < 4; ++nt)
#pragma unroll
            for (int r2 = 0; r2 < 4; ++r2) {
                int row_l = wm + mt * 16 + quad * 4 + r2;
                int col_l = wn + nt * 16 + l16;
                smem[row_l * 128 + col_l] = __float2bfloat16(acc[mt][nt][r2] + bv[nt]);
            }
    __syncthreads();
#pragma unroll
    for (int p = 0; p < TM / 16; ++p) {
        int idx = p * 256 + tid;
        int row = m0 + (idx >> 4);
        if (row < M)
            *(short8*)(C + (size_t)row * ldc + n0 + (idx & 15) * 8) =
                *(const short8*)(smem + idx * 8);
    }
}

// ---------------------------------------------------------------------------
// Flash attention v7 (unchanged from round 8)
// ---------------------------------------------------------------------------
__global__ __launch_bounds__(256) void attn_flash3(
    const BF16* __restrict__ Q, const BF16* __restrict__ K,
    const BF16* __restrict__ VT, BF16* __restrict__ O)
{
    constexpr int NQ = 729, HDk = 96, DM = 1152, LDV = 768;
    __shared__ __align__(16) BF16 Ks[64 * 104];
    __shared__ __align__(16) BF16 Vs[112 * 64];
    __shared__ __align__(16) BF16 Ps[4][16 * 64];

    const int id = blockIdx.x;
    const int xcd = id & 7, slot = id >> 3;        // slot 0..143
    const int hb = slot / 12, qt = slot - hb * 12; // hb 0..11, qt 0..11
    const int hg = xcd * 12 + hb;
    const int b = hg / 12, hh = hg - b * 12;

    const int tid = threadIdx.x, wave = tid >> 6, lane = tid & 63;
    const int quad = lane >> 4, l16 = lane & 15;
    const size_t kbase = (size_t)b * (NQ * DM) + (size_t)hh * (NQ * HDk);
    const size_t vbase = (size_t)hg * 112 * LDV;

    const short8 zero8 = {0, 0, 0, 0, 0, 0, 0, 0};
    const v4f zf = {0.f, 0.f, 0.f, 0.f};
    const float C2 = 0.14724445f;   // (1/sqrt(96)) * log2(e)

    const int q0w = qt * 64 + wave * 16;
    short8 aq[3];
    {
        int qrow = q0w + l16;
#pragma unroll
        for (int ks = 0; ks < 3; ++ks)
            aq[ks] = (qrow < NQ)
                ? *(const short8*)(Q + kbase + (size_t)qrow * HDk + ks * 32 + quad * 8)
                : zero8;
    }

    int kk_[3], kg_[3];
#pragma unroll
    for (int i = 0; i < 3; ++i) {
        int c = tid + i * 256;
        kk_[i] = c / 12; kg_[i] = c - kk_[i] * 12;
    }
    int vq_[4], vgr_[4], vhd_[4];
#pragma unroll
    for (int i = 0; i < 4; ++i) {
        int q = wave + 4 * i;
        vq_[i] = q;
        int hd = q * 8 + (lane >> 3);
        vhd_[i] = hd;
        vgr_[i] = ((lane & 7) - hd) & 7;
    }

    v4f oacc[7];
#pragma unroll
    for (int nt = 0; nt < 7; ++nt) oacc[nt] = zf;

    // prologue: K(0) into registers
    short8 kreg[3];
#pragma unroll
    for (int i = 0; i < 3; ++i)
        kreg[i] = *(const short8*)(K + kbase + (size_t)kk_[i] * HDk + kg_[i] * 8);

    for (int kt = 0; kt < 12; ++kt) {
        const int k0 = kt * 64;
#pragma unroll
        for (int i = 0; i < 3; ++i)
            *(short8*)(Ks + kk_[i] * 104 + kg_[i] * 8) = kreg[i];
#pragma unroll
        for (int i = 0; i < 4; ++i) {
            if (vq_[i] < 14)
                async_cp16(VT + vbase + (size_t)vhd_[i] * LDV + k0 + vgr_[i] * 8,
                           Vs + vq_[i] * 512);
        }
        asm volatile("s_waitcnt lgkmcnt(0)" ::: "memory");
        __builtin_amdgcn_s_barrier();
        __builtin_amdgcn_sched_barrier(0);
        {
            const int kn = (kt < 11) ? (k0 + 64) : 0;
#pragma unroll
            for (int i = 0; i < 3; ++i)
                kreg[i] = *(const short8*)(K + kbase + (size_t)(kn + kk_[i]) * HDk + kg_[i] * 8);
        }

        v4f s[4];
#pragma unroll
        for (int nt = 0; nt < 4; ++nt) s[nt] = zf;
        __builtin_amdgcn_s_setprio(1);
#pragma unroll
        for (int ks = 0; ks < 3; ++ks)
#pragma unroll
            for (int nt = 0; nt < 4; ++nt) {
                short8 bk = *(const short8*)(Ks + (nt * 16 + l16) * 104 + ks * 32 + quad * 8);
                s[nt] = __builtin_amdgcn_mfma_f32_16x16x32_bf16(aq[ks], bk, s[nt], 0, 0, 0);
            }
        __builtin_amdgcn_s_setprio(0);

        BF16* Pw = &Ps[wave][0];
#pragma unroll
        for (int nt = 0; nt < 4; ++nt)
#pragma unroll
            for (int r = 0; r < 4; ++r)
                Pw[((quad * 4 + r) << 6)
                   + ((((nt << 1) | (l16 >> 3)) ^ (quad << 1)) << 3)
                   + (l16 & 7)] =
                    __float2bfloat16(exp2f(s[nt][r] * C2));
        asm volatile("s_waitcnt lgkmcnt(0)" ::: "memory");

        short8 ap[2];
#pragma unroll
        for (int kc = 0; kc < 2; ++kc)
            ap[kc] = *(const short8*)(Pw + (l16 << 6)
                + ((((kc << 2) | quad) ^ (((l16 >> 2) & 3) << 1)) << 3));

        asm volatile("s_waitcnt vmcnt(3)" ::: "memory");
        __builtin_amdgcn_s_barrier();
        __builtin_amdgcn_sched_barrier(0);

        __builtin_amdgcn_s_setprio(1);
#pragma unroll
        for (int nt = 0; nt < 7; ++nt) {
            int hd = nt * 16 + l16;
#pragma unroll
            for (int kc = 0; kc < 2; ++kc) {
                short8 bv = *(const short8*)(Vs + hd * 64 + (((kc * 4 + quad) + hd & 7) & 7) * 8);
                oacc[nt] = __builtin_amdgcn_mfma_f32_16x16x32_bf16(ap[kc], bv, oacc[nt], 0, 0, 0);
            }
        }
        __builtin_amdgcn_s_setprio(0);
        asm volatile("s_waitcnt lgkmcnt(0)" ::: "memory");
        __builtin_amdgcn_s_barrier();
        __builtin_amdgcn_sched_barrier(0);
    }

    {
        const int qb = q0w + quad * 4;
#pragma unroll
        for (int r = 0; r < 4; ++r) {
            int q = qb + r;
            float lv = __shfl(oacc[6][r], quad << 4, 64);
            float inv = (lv > 0.f) ? 1.f / lv : 0.f;
            if (q >= NQ) continue;
#pragma unroll
            for (int nt = 0; nt < 6; ++nt)
                O[(size_t)b * (NQ * DM) + (size_t)q * DM + hh * HDk + nt * 16 + l16] =
                    __float2bfloat16(oacc[nt][r] * inv);
        }
    }
}

// ---------------------------------------------------------------------------
// LayerNorm fused kernels (192 threads, exp2-gelu — unchanged)
// ---------------------------------------------------------------------------
__device__ __forceinline__ float block_sum192(float v, float* red, int tid)
{
#pragma unroll
    for (int mm = 1; mm < 64; mm <<= 1) v += __shfl_xor(v, mm, 64);
    if ((tid & 63) == 0) red[tid >> 6] = v;
    __syncthreads();
    float r = red[0] + red[1] + red[2];
    __syncthreads();
    return r;
}

__global__ __launch_bounds__(192) void ln1_gelu_kernel(
    const BF16* __restrict__ ao, const float* __restrict__ x,
    const float* __restrict__ gw, const float* __restrict__ bw,
    BF16* __restrict__ hout, BF16* __restrict__ gout)
{
    __shared__ float red[3];
    const int row = blockIdx.x, tid = threadIdx.x;
    const bool act = tid < 144;                 // 144 * 8 = 1152
    float v[8];
    float s = 0.f;
    if (act) {
        short8 pk = ((const short8*)(ao + (size_t)row * 1152))[tid];
#pragma unroll
        for (int j = 0; j < 8; ++j) { v[j] = bs2f(pk[j]); s += v[j]; }
    } else {
#pragma unroll
        for (int j = 0; j < 8; ++j) v[j] = 0.f;
    }
    s = block_sum192(s, red, tid);
    float mu = s * (1.f / 1152.f);
    float vsum = 0.f;
    if (act) {
#pragma unroll
        for (int j = 0; j < 8; ++j) { float d = v[j] - mu; vsum += d * d; }
    }
    vsum = block_sum192(vsum, red, tid);
    float rstd = rsqrtf(vsum * (1.f / 1152.f) + 1e-6f);
    if (act) {
        f4 g0 = ((const f4*)gw)[2 * tid], g1 = ((const f4*)gw)[2 * tid + 1];
        f4 b0 = ((const f4*)bw)[2 * tid], b1 = ((const f4*)bw)[2 * tid + 1];
        const f4* xr = (const f4*)(x + (size_t)row * 1152);
        f4 x0 = xr[2 * tid], x1 = xr[2 * tid + 1];
        short8 ho, go;
#pragma unroll
        for (int j = 0; j < 8; ++j) {
            float gj = (j < 4) ? g0[j] : g1[j - 4];
            float bj = (j < 4) ? b0[j] : b1[j - 4];
            float xj = (j < 4) ? x0[j] : x1[j - 4];
            float hv = (v[j] - mu) * rstd * gj + bj + xj;
            ho[j] = f2bs(hv);
            float z2 = 2.3022077f * hv + 0.10294636f * hv * hv * hv;
            float gl = hv / (1.f + exp2f(-z2));
            go[j] = f2bs(gl);
        }
        ((short8*)(hout + (size_t)row * 1152))[tid] = ho;
        ((short8*)(gout + (size_t)row * 1152))[tid] = go;
    }
}

__global__ __launch_bounds__(192) void ln2_kernel(
    const BF16* __restrict__ m2, const BF16* __restrict__ hf,
    const float* __restrict__ gw, const float* __restrict__ bw,
    float* __restrict__ out)
{
    __shared__ float red[3];
    const int row = blockIdx.x, tid = threadIdx.x;
    const bool act = tid < 144;
    float v[8];
    float s = 0.f;
    if (act) {
        short8 pk = ((const short8*)(m2 + (size_t)row * 1152))[tid];
#pragma unroll
        for (int j = 0; j < 8; ++j) { v[j] = bs2f(pk[j]); s += v[j]; }
    } else {
#pragma unroll
        for (int j = 0; j < 8; ++j) v[j] = 0.f;
    }
    s = block_sum192(s, red, tid);
    float mu = s * (1.f / 1152.f);
    float vsum = 0.f;
    if (act) {
#pragma unroll
        for (int j = 0; j < 8; ++j) { float d = v[j] - mu; vsum += d * d; }
    }
    vsum = block_sum192(vsum, red, tid);
    float rstd = rsqrtf(vsum * (1.f / 1152.f) + 1e-6f);
    if (act) {
        f4 g0 = ((const f4*)gw)[2 * tid], g1 = ((const f4*)gw)[2 * tid + 1];
        f4 b0 = ((const f4*)bw)[2 * tid], b1 = ((const f4*)bw)[2 * tid + 1];
        short8 hfv = ((const short8*)(hf + (size_t)row * 1152))[tid];
        f4 o0, o1;
#pragma unroll
        for (int j = 0; j < 8; ++j) {
            float gj = (j < 4) ? g0[j] : g1[j - 4];
            float bj = (j < 4) ? b0[j] : b1[j - 4];
            float ov = (v[j] - mu) * rstd * gj + bj + bs2f(hfv[j]);
            if (j < 4) o0[j] = ov; else o1[j - 4] = ov;
        }
        f4* orow = (f4*)(out + (size_t)row * 1152);
        orow[2 * tid] = o0;
        orow[2 * tid + 1] = o1;
    }
}

// ---------------------------------------------------------------------------
// Workspace layout (~125 MB): unchanged.
// ---------------------------------------------------------------------------
extern "C" void kernel_launch(void* const* d_in, const int* in_sizes, int n_in,
                              void* d_out, int out_size, void* d_ws, size_t ws_size,
                              hipStream_t stream)
{
    const float* x    = (const float*)d_in[0];
    const float* wq   = (const float*)d_in[1];
    const float* bq   = (const float*)d_in[2];
    const float* wk   = (const float*)d_in[3];
    const float* bk   = (const float*)d_in[4];
    const float* wv   = (const float*)d_in[5];
    const float* bv   = (const float*)d_in[6];
    const float* wo   = (const float*)d_in[7];
    const float* bo   = (const float*)d_in[8];
    const float* ln1g = (const float*)d_in[9];
    const float* ln1b = (const float*)d_in[10];
    const float* wfc1 = (const float*)d_in[11];
    const float* bfc1 = (const float*)d_in[12];
    const float* wfc2 = (const float*)d_in[13];
    const float* bfc2 = (const float*)d_in[14];
    const float* ln2g = (const float*)d_in[15];
    const float* ln2b = (const float*)d_in[16];

    const int T = 8 * 729;           // 5832
    const int D = 1152, HIDP = 4352;
    const size_t TD = (size_t)T * D;
    const size_t WDD = (size_t)D * D;

    BF16* wbq   = (BF16*)d_ws;
    BF16* wbk   = wbq + WDD;
    BF16* wbv   = wbk + WDD;
    BF16* wbo   = wbv + WDD;
    BF16* wbf1t = wbo + WDD;                   // [1152][4352] (W1^T)
    BF16* wbf2  = wbf1t + (size_t)HIDP * D;    // [1152][4352]
    BF16* xb    = wbf2 + (size_t)D * HIDP;
    BF16* S0    = xb + TD;
    BF16* S1    = S0 + TD;
    BF16* S2    = S1 + TD;
    BF16* S3    = S2 + TD;
    BF16* C0    = S3 + TD;
    BF16* C1    = C0 + TD;
    BF16* VT    = C0;                          // [96*112*768] overlays C0+C1 head

    static float* bp_dev = nullptr;
    static BF16*  wm_dev = nullptr;
    if (!bp_dev) hipGetSymbolAddress((void**)&bp_dev, HIP_SYMBOL(g_bp));
    if (!wm_dev) hipGetSymbolAddress((void**)&wm_dev, HIP_SYMBOL(g_wm));

    dim3 blk(256);

    // L1: converts + W1^T + fused bias
    prep_kernel<<<18153, blk, 0, stream>>>(
        wq, wk, wv, wo, wfc1, wfc2, x, bfc1, bfc2,
        wbq, wbk, wbv, wbo, wbf1t, wbf2, xb);

    // L2: weight-merge (128², 2-phase) || fused QKV (256², 8-phase)
    qkv_wm8_kernel<<<403, dim3(512), 0, stream>>>(
        xb, wbq, bq, bk, bv, S0, TD, T, wbf2, wbf1t);

    // L3: V transpose + VT tail init
    trans_kernel<<<1728, blk, 0, stream>>>(S2, VT);

    // L4: attention (v7: 64-row q-tiles, grid 1152)
    attn_flash3<<<1152, blk, 0, stream>>>(S0, S1, VT, S3);

    // L5: output projection (TM=224: 27x9 = 243 blocks, one round)
    gemm_bt_t<224><<<243, blk, 0, stream>>>(S3, D, wbo, D, bo, D, C0, D, T, D, 9);

    // L6: LN1 + residual + gelu (192 threads)
    ln1_gelu_kernel<<<T, dim3(192), 0, stream>>>(C0, x, ln1g, ln1b, C1, C0);

    // L7: merged-MLP apply (TM=224)
    gemm_bt_t<224><<<243, blk, 0, stream>>>(C0, D, wm_dev, D, bp_dev, D, S3, D, T, D, 9);

    // L8: LN2 + residual -> d_out (fp32, 192 threads)
    ln2_kernel<<<T, dim3(192), 0, stream>>>(S3, C1, ln2g, ln2b, (float*)d_out);
}

// Round 10
// 378.128 us; speedup vs baseline: 1.0310x; 1.0310x over previous
//
#include <hip/hip_runtime.h>
#include <hip/hip_bf16.h>

#define BF16 __hip_bfloat16

typedef short short8 __attribute__((ext_vector_type(8)));
typedef short short4v __attribute__((ext_vector_type(4)));
typedef float v4f __attribute__((ext_vector_type(4)));
typedef float f4 __attribute__((ext_vector_type(4)));

__device__ float g_bp[1152];          // fused MLP bias (W2*b1 + b2)
__device__ BF16  g_wm[1152 * 1152];   // merged MLP weight (W2*W1), bf16

__device__ __forceinline__ short f2bs(float f) {
    __hip_bfloat16 h = __float2bfloat16(f);
    return *(short*)&h;
}

__device__ __forceinline__ float bs2f(short s) {
    __hip_bfloat16 h = *(__hip_bfloat16*)&s;
    return __bfloat162float(h);
}

// async global->LDS 16B copy (LDS dest: wave-uniform base + lane*16B)
__device__ __forceinline__ void async_cp16(const BF16* g, BF16* l) {
    __builtin_amdgcn_global_load_lds(
        (const __attribute__((address_space(1))) void*)g,
        (__attribute__((address_space(3))) void*)l,
        16, 0, 0);
}

// m204 bijective XCD-chunked swizzle
__device__ __forceinline__ int xcd_chunk(int u, int nwg) {
    int xcd = u & 7, i = u >> 3;
    int q = nwg >> 3, r = nwg & 7;
    return (xcd < r ? xcd * (q + 1) : r * (q + 1) + (xcd - r) * q) + i;
}

// ---------------------------------------------------------------------------
// L1 prep (unchanged)
// ---------------------------------------------------------------------------
__global__ __launch_bounds__(256) void prep_kernel(
    const float* __restrict__ wq, const float* __restrict__ wk,
    const float* __restrict__ wv, const float* __restrict__ wo,
    const float* __restrict__ wfc1, const float* __restrict__ wfc2,
    const float* __restrict__ x,
    const float* __restrict__ bfc1, const float* __restrict__ bfc2,
    BF16* __restrict__ wbq, BF16* __restrict__ wbk,
    BF16* __restrict__ wbv, BF16* __restrict__ wbo,
    BF16* __restrict__ wbf1t, BF16* __restrict__ wbf2,
    BF16* __restrict__ xb)
{
    __shared__ float tile[64][65];
    const int bid = blockIdx.x;
    const int tid = threadIdx.x;

    if (bid < 16641) {
        const int i = bid * 256 + tid;
        constexpr int N_DD  = 331776;
        constexpr int N4    = 4 * N_DD;
        constexpr int N_F2  = 1253376;
        constexpr int E_F2  = N4 + N_F2;
        constexpr int N_X   = 1679616;
        constexpr int TOTAL = E_F2 + N_X;

        if (i < N4) {
            int seg = i / N_DD, j = i - seg * N_DD;
            const float* s = (seg == 0) ? wq : (seg == 1) ? wk : (seg == 2) ? wv : wo;
            BF16* d = (seg == 0) ? wbq : (seg == 1) ? wbk : (seg == 2) ? wbv : wbo;
            f4 v = ((const f4*)s)[j];
            short4v o = {f2bs(v.x), f2bs(v.y), f2bs(v.z), f2bs(v.w)};
            ((short4v*)d)[j] = o;
        } else if (i < E_F2) {
            int j = i - N4;
            int row = j / 1088;
            int c = (j - row * 1088) * 4;
            short4v o = {0, 0, 0, 0};
            if (c < 4304) {
                f4 v = *(const f4*)(wfc2 + (size_t)row * 4304 + c);
                o[0] = f2bs(v.x); o[1] = f2bs(v.y); o[2] = f2bs(v.z); o[3] = f2bs(v.w);
            }
            *(short4v*)(wbf2 + (size_t)row * 4352 + c) = o;
        } else if (i < TOTAL) {
            int j = i - E_F2;
            f4 v = ((const f4*)x)[j];
            short4v o = {f2bs(v.x), f2bs(v.y), f2bs(v.z), f2bs(v.w)};
            ((short4v*)xb)[j] = o;
        }
    } else if (bid < 17865) {
        const int b2 = bid - 16641;
        const int h0 = (b2 % 68) * 64;
        const int d0 = (b2 / 68) * 64;
#pragma unroll
        for (int i = 0; i < 4; ++i) {
            int lin = tid + i * 256;
            int r = lin >> 4, c4 = lin & 15;
            f4 v = {0.f, 0.f, 0.f, 0.f};
            if (h0 + r < 4304)
                v = *(const f4*)(wfc1 + (size_t)(h0 + r) * 1152 + d0 + c4 * 4);
            tile[r][c4 * 4 + 0] = v.x;
            tile[r][c4 * 4 + 1] = v.y;
            tile[r][c4 * 4 + 2] = v.z;
            tile[r][c4 * 4 + 3] = v.w;
        }
        __syncthreads();
#pragma unroll
        for (int i = 0; i < 2; ++i) {
            int lin = tid + i * 256;
            int dr = lin >> 3, h8 = lin & 7;
            short8 o;
#pragma unroll
            for (int e = 0; e < 8; ++e)
                o[e] = f2bs(tile[h8 * 8 + e][dr]);
            *(short8*)(wbf1t + (size_t)(d0 + dr) * 4352 + h0 + h8 * 8) = o;
        }
    } else {
        const int row = (bid - 17865) * 4 + (tid >> 6);
        const int lane = tid & 63;
        const float* wr = wfc2 + (size_t)row * 4304;
        float s = 0.f;
        for (int k = lane; k < 4304; k += 64) s += wr[k] * bfc1[k];
#pragma unroll
        for (int mm = 1; mm < 64; mm <<= 1) s += __shfl_xor(s, mm, 64);
        if (lane == 0) g_bp[row] = s + bfc2[row];
    }
}

// ---------------------------------------------------------------------------
// L2: [0,162) weight-merge SPLIT-K z=2 (128x128 tile, 34 ksteps each, fp32
//     partial planes on S3 — merge was the 3.8q critical path at z=1,
//     80 µs makespan; z=2 cuts it to ~2.9q).
//     [162,484) fused QKV 256x256 8-phase (unchanged schedule).
// ---------------------------------------------------------------------------
__global__ __launch_bounds__(512, 2) void qkv_wm8_kernel(
    const BF16* __restrict__ A,
    const BF16* __restrict__ Wqkv,
    const float* __restrict__ b0, const float* __restrict__ b1,
    const float* __restrict__ b2,
    BF16* __restrict__ C, size_t cstride, int M,
    const BF16* __restrict__ W2,
    const BF16* __restrict__ W1t,
    float* __restrict__ P)             // 2 planes [1152][1152] fp32 (on S3)
{
    __shared__ __align__(16) BF16 smem[65536];   // 128 KiB
    const int bid  = blockIdx.x;
    const int tid  = threadIdx.x;
    const int lane = tid & 63;
    const int wave = tid >> 6;
    const int quad = lane >> 4;
    const int l16  = lane & 15;
    const v4f zf = {0.f, 0.f, 0.f, 0.f};

    int rr[2], sw[2], lo[2];
#pragma unroll
    for (int j = 0; j < 2; ++j) {
        int c = tid + j * 512;
        rr[j] = c >> 3;
        sw[j] = (((c & 7) - (c >> 3)) & 7) << 3;
        lo[j] = (c & ~63) * 8;
    }

    if (bid < 162) {
        // ---- weight merge split-K: plane mz, ksteps [mz*34, mz*34+34) ----
        BF16* Am = smem;
        BF16* Bm = smem + 8192;
        const int mz  = bid / 81;
        const int idx = bid - mz * 81;
        const int m0 = (idx % 9) * 128;
        const int n0 = (idx / 9) * 128;
        const int ks0 = mz * 34;
        const int wm = (wave >> 1) * 32;
        const int wn = (wave & 1) * 64;

        v4f acc[2][4];
#pragma unroll
        for (int i = 0; i < 2; ++i)
#pragma unroll
            for (int j = 0; j < 4; ++j) acc[i][j] = zf;

        const BF16* gA[2]; const BF16* gB[2];
#pragma unroll
        for (int j = 0; j < 2; ++j) {
            gA[j] = W2 + (size_t)(m0 + rr[j]) * 4352 + ks0 * 64 + sw[j];
            gB[j] = W1t + (size_t)(n0 + rr[j]) * 4352 + ks0 * 64 + sw[j];
        }

        for (int kt = 0; kt < 34; ++kt) {
#pragma unroll
            for (int j = 0; j < 2; ++j) { async_cp16(gA[j], Am + lo[j]); gA[j] += 64; }
#pragma unroll
            for (int j = 0; j < 2; ++j) { async_cp16(gB[j], Bm + lo[j]); gB[j] += 64; }
            __syncthreads();
#pragma unroll
            for (int ks = 0; ks < 2; ++ks) {
                short8 af[2], bfg[4];
#pragma unroll
                for (int mt = 0; mt < 2; ++mt) {
                    int row = wm + mt * 16 + l16;
                    af[mt] = *(const short8*)(Am + row * 64 + ((((ks << 2) | quad) + row & 7) & 7) * 8);
                }
#pragma unroll
                for (int nt = 0; nt < 4; ++nt) {
                    int row = wn + nt * 16 + l16;
                    bfg[nt] = *(const short8*)(Bm + row * 64 + ((((ks << 2) | quad) + row & 7) & 7) * 8);
                }
#pragma unroll
                for (int mt = 0; mt < 2; ++mt)
#pragma unroll
                    for (int nt = 0; nt < 4; ++nt)
                        acc[mt][nt] = __builtin_amdgcn_mfma_f32_16x16x32_bf16(
                            af[mt], bfg[nt], acc[mt][nt], 0, 0, 0);
            }
            __syncthreads();
        }

        float* Pz = P + (size_t)mz * 1327104;   // 1152*1152
#pragma unroll
        for (int mt = 0; mt < 2; ++mt)
#pragma unroll
            for (int nt = 0; nt < 4; ++nt)
#pragma unroll
                for (int r2 = 0; r2 < 4; ++r2) {
                    int row = m0 + wm + mt * 16 + quad * 4 + r2;
                    int col = n0 + wn + nt * 16 + l16;
                    Pz[(size_t)row * 1152 + col] = acc[mt][nt][r2];
                }
    } else {
        const int wg = xcd_chunk(bid - 162, 322);
        const int m0 = (wg / 14) * 256;
        const int n0 = (wg % 14) * 256;
        const int wr = wave >> 2;
        const int wc = wave & 3;
        BF16* As = smem;
        BF16* Bs = smem + 32768;

        v4f acc[8][4];
#pragma unroll
        for (int i = 0; i < 8; ++i)
#pragma unroll
            for (int j = 0; j < 4; ++j) acc[i][j] = zf;

        #define STAGE_A(dd, hh, tt)                                            \
            {                                                                  \
                _Pragma("unroll")                                              \
                for (int j = 0; j < 2; ++j)                                    \
                    async_cp16(A + (size_t)(m0 + (hh) * 128 + rr[j]) * 1152    \
                                 + (tt) * 64 + sw[j],                          \
                               As + (dd) * 16384 + (hh) * 8192 + lo[j]);       \
            }
        #define STAGE_B(dd, hh, tt)                                            \
            {                                                                  \
                _Pragma("unroll")                                              \
                for (int j = 0; j < 2; ++j)                                    \
                    async_cp16(Wqkv + (size_t)(n0 + (hh) * 128 + rr[j]) * 1152 \
                                 + (tt) * 64 + sw[j],                          \
                               Bs + (dd) * 16384 + (hh) * 8192 + lo[j]);       \
            }

        STAGE_B(0, 0, 0); STAGE_B(0, 1, 0);
        STAGE_A(0, 0, 0); STAGE_A(0, 1, 0);
        STAGE_B(1, 0, 1); STAGE_B(1, 1, 1);
        asm volatile("s_waitcnt vmcnt(4)" ::: "memory");
        __builtin_amdgcn_s_barrier();
        __builtin_amdgcn_sched_barrier(0);

        short8 bfr[4][2], afr[2][2];
#pragma unroll 2
        for (int it = 0; it < 18; ++it) {
            const int d = it & 1;
            const BF16* Ad = As + d * 16384;
            const BF16* Bd = Bs + d * 16384;
#pragma unroll
            for (int q = 0; q < 4; ++q) {
                if (q == 0) {
#pragma unroll
                    for (int nt = 0; nt < 4; ++nt) {
                        int R = wc * 64 + nt * 16 + l16;
#pragma unroll
                        for (int ks = 0; ks < 2; ++ks)
                            bfr[nt][ks] = *(const short8*)(
                                Bd + R * 64 + ((((ks << 2) | quad) + R & 7) & 7) * 8);
                    }
                }
#pragma unroll
                for (int mi = 0; mi < 2; ++mi) {
                    int R = wr * 128 + (q * 2 + mi) * 16 + l16;
#pragma unroll
                    for (int ks = 0; ks < 2; ++ks)
                        afr[mi][ks] = *(const short8*)(
                            Ad + R * 64 + ((((ks << 2) | quad) + R & 7) & 7) * 8);
                }
                if (q == 0) { if (it + 1 < 18) STAGE_A(d ^ 1, 0, it + 1); }
                if (q == 1) { if (it + 1 < 18) STAGE_A(d ^ 1, 1, it + 1); }
                if (q == 2) { if (it + 2 < 18) STAGE_B(d,     0, it + 2); }
                if (q == 3) { if (it + 2 < 18) STAGE_B(d,     1, it + 2); }

                __builtin_amdgcn_s_barrier();
                asm volatile("s_waitcnt lgkmcnt(0)" ::: "memory");
                __builtin_amdgcn_sched_barrier(0);
                __builtin_amdgcn_s_setprio(1);
#pragma unroll
                for (int ks = 0; ks < 2; ++ks)
#pragma unroll
                    for (int mi = 0; mi < 2; ++mi)
#pragma unroll
                        for (int nt = 0; nt < 4; ++nt)
                            acc[q * 2 + mi][nt] = __builtin_amdgcn_mfma_f32_16x16x32_bf16(
                                afr[mi][ks], bfr[nt][ks], acc[q * 2 + mi][nt], 0, 0, 0);
                __builtin_amdgcn_s_setprio(0);
                if (q == 3) {
                    if (it + 2 < 18)
                        asm volatile("s_waitcnt vmcnt(4)" ::: "memory");
                    else
                        asm volatile("s_waitcnt vmcnt(0)" ::: "memory");
                }
                __builtin_amdgcn_s_barrier();
            }
        }
        #undef STAGE_A
        #undef STAGE_B

        float bv[4];
#pragma unroll
        for (int nt = 0; nt < 4; ++nt) {
            int col_g = n0 + wc * 64 + nt * 16 + l16;
            int sel = (col_g >= 2304) ? 2 : (col_g >= 1152) ? 1 : 0;
            const float* bp = (sel == 0) ? b0 : (sel == 1) ? b1 : b2;
            bv[nt] = (col_g < 3456) ? bp[col_g - sel * 1152] : 0.f;
        }
#pragma unroll
        for (int mt = 0; mt < 8; ++mt)
#pragma unroll
            for (int nt = 0; nt < 4; ++nt)
#pragma unroll
                for (int r2 = 0; r2 < 4; ++r2) {
                    int row_l = wr * 128 + mt * 16 + quad * 4 + r2;
                    int col_l = wc * 64 + nt * 16 + l16;
                    smem[row_l * 256 + col_l] = __float2bfloat16(acc[mt][nt][r2] + bv[nt]);
                }
        __syncthreads();
#pragma unroll
        for (int p = 0; p < 16; ++p) {
            int idx = p * 512 + tid;
            int row = m0 + (idx >> 5);
            int col_g = n0 + (idx & 31) * 8;
            if (row < M && col_g < 3456) {
                int sel = (col_g >= 2304) ? 2 : (col_g >= 1152) ? 1 : 0;
                *(short8*)(C + (size_t)sel * cstride + (size_t)row * 1152
                           + col_g - sel * 1152) =
                    *(const short8*)(smem + idx * 8);
            }
        }
    }
}

// ---------------------------------------------------------------------------
// L3: [0,1152) V transpose | [1152,1728) VT tail | [1728,3024) Wm reduce
// ---------------------------------------------------------------------------
__global__ __launch_bounds__(256) void trans_kernel(
    const BF16* __restrict__ V, BF16* __restrict__ VT,
    const float* __restrict__ P, BF16* __restrict__ Wm)
{
    __shared__ __align__(16) BF16 tl[64][128];
    const int bid = blockIdx.x, tid = threadIdx.x;
    const short8 zero8 = {0, 0, 0, 0, 0, 0, 0, 0};

    if (bid < 1152) {
        const int hg = bid / 12, kb = bid - hg * 12;
        const int b = hg / 12, hh = hg - b * 12;
        const BF16* src = V + (size_t)b * 839808 + (size_t)hh * 69984;
        BF16* dst = VT + (size_t)hg * 86016;
        const int kk0 = kb * 64;
#pragma unroll
        for (int i = 0; i < 3; ++i) {
            int c = tid + i * 256;
            int r = c / 12, cg = c - r * 12;
            short8 v = (kk0 + r < 729)
                ? *(const short8*)(src + (size_t)(kk0 + r) * 96 + cg * 8) : zero8;
            *(short8*)(&tl[r][(cg ^ ((r >> 3) & 7)) * 8]) = v;
        }
        __syncthreads();
#pragma unroll
        for (int i = 0; i < 3; ++i) {
            int wc = tid + i * 256;
            int hd = wc >> 3, o = wc & 7;
            int sp = (((hd >> 3) ^ o) << 3) + (hd & 7);
            short8 out;
#pragma unroll
            for (int j = 0; j < 8; ++j)
                out[j] = *(const short*)&tl[o * 8 + j][sp];
            *(short8*)(dst + (size_t)hd * 768 + kk0 + o * 8) = out;
        }
    } else if (bid < 1728) {
        int c = (bid - 1152) * 256 + tid;
        int hg = c / 1536, rem = c - hg * 1536;
        int r = rem / 96, ock = rem - r * 96;
        int kk = ock * 8;
        short8 v = zero8;
        if (r == 0) {
            const short oneb = 0x3F80;
#pragma unroll
            for (int j = 0; j < 8; ++j) v[j] = (kk + j < 729) ? oneb : (short)0;
        }
        *(short8*)(VT + (size_t)hg * 86016 + (size_t)(96 + r) * 768 + kk) = v;
    } else {
        int i = (bid - 1728) * 256 + tid;        // f4 idx < 331776
        f4 s = ((const f4*)P)[i];
        f4 v = ((const f4*)(P + 1327104))[i];
        s.x += v.x; s.y += v.y; s.z += v.z; s.w += v.w;
        short4v o = {f2bs(s.x), f2bs(s.y), f2bs(s.z), f2bs(s.w)};
        ((short4v*)Wm)[i] = o;
    }
}

// ---------------------------------------------------------------------------
// GEMM (TM x 128, XCD-chunked). TM=64 for WO/apply — 828 blocks ≈ 3.2/CU;
// r9 proved TM=224 (1 block/CU, 1 wave/SIMD) loses to TLP.
// ---------------------------------------------------------------------------
template<int TM>
__global__ __launch_bounds__(256) void gemm_bt_t(
    const BF16* __restrict__ A, int lda,
    const BF16* __restrict__ W, int ldb,
    const float* __restrict__ bias, int nbias,
    BF16* __restrict__ C, int ldc,
    int M, int Kr, int nbn)
{
    constexpr int MT = TM / 32;
    __shared__ __align__(16) BF16 smem[(TM + 128) * 64];
    BF16* As = smem;
    BF16* Bs = smem + TM * 64;

    const int tid  = threadIdx.x;
    const int lane = tid & 63;
    const int wave = tid >> 6;
    const int quad = lane >> 4;
    const int l16  = lane & 15;
    const int wm   = (wave >> 1) * (TM / 2);
    const int wn   = (wave & 1) * 64;
    const int wg   = xcd_chunk(blockIdx.x, gridDim.x);
    const int m0   = (wg / nbn) * TM;
    const int n0   = (wg % nbn) * 128;
    if (m0 >= M) return;

    const v4f zf = {0.f, 0.f, 0.f, 0.f};
    v4f acc[MT][4];
#pragma unroll
    for (int i = 0; i < MT; ++i)
#pragma unroll
        for (int j = 0; j < 4; ++j) acc[i][j] = zf;

    const BF16* gA[MT]; BF16* lA[MT];
#pragma unroll
    for (int i = 0; i < MT; ++i) {
        int c = tid + i * 256;
        gA[i] = A + (size_t)(m0 + (c >> 3)) * lda + ((((c & 7) - (c >> 3)) & 7) << 3);
        lA[i] = As + (c & ~63) * 8;
    }
    const BF16* gB[4]; BF16* lB[4];
#pragma unroll
    for (int i = 0; i < 4; ++i) {
        int c = tid + i * 256;
        gB[i] = W + (size_t)(n0 + (c >> 3)) * ldb + ((((c & 7) - (c >> 3)) & 7) << 3);
        lB[i] = Bs + (c & ~63) * 8;
    }

    const int nk = Kr >> 6;
    for (int kt = 0; kt < nk; ++kt) {
#pragma unroll
        for (int i = 0; i < MT; ++i) { async_cp16(gA[i], lA[i]); gA[i] += 64; }
#pragma unroll
        for (int i = 0; i < 4; ++i)  { async_cp16(gB[i], lB[i]); gB[i] += 64; }
        __syncthreads();

#pragma unroll
        for (int ks = 0; ks < 2; ++ks) {
            short8 af[MT], bfg[4];
#pragma unroll
            for (int mt = 0; mt < MT; ++mt) {
                int row = wm + mt * 16 + l16;
                af[mt] = *(const short8*)(As + row * 64 + ((((ks << 2) | quad) + row & 7) & 7) * 8);
            }
#pragma unroll
            for (int nt = 0; nt < 4; ++nt) {
                int row = wn + nt * 16 + l16;
                bfg[nt] = *(const short8*)(Bs + row * 64 + ((((ks << 2) | quad) + row & 7) & 7) * 8);
            }
#pragma unroll
            for (int mt = 0; mt < MT; ++mt)
#pragma unroll
                for (int nt = 0; nt < 4; ++nt)
                    acc[mt][nt] = __builtin_amdgcn_mfma_f32_16x16x32_bf16(
                        af[mt], bfg[nt], acc[mt][nt], 0, 0, 0);
        }
        __syncthreads();
    }

    float bv[4];
#pragma unroll
    for (int nt = 0; nt < 4; ++nt) {
        int col = n0 + wn + nt * 16 + l16;
        bv[nt] = (col < nbias) ? bias[col] : 0.f;
    }
#pragma unroll
    for (int mt = 0; mt < MT; ++mt)
#pragma unroll
        for (int nt = 0; nt < 4; ++nt)
#pragma unroll
            for (int r2 = 0; r2 < 4; ++r2) {
                int row_l = wm + mt * 16 + quad * 4 + r2;
                int col_l = wn + nt * 16 + l16;
                smem[row_l * 128 + col_l] = __float2bfloat16(acc[mt][nt][r2] + bv[nt]);
            }
    __syncthreads();
#pragma unroll
    for (int p = 0; p < TM / 16; ++p) {
        int idx = p * 256 + tid;
        int row = m0 + (idx >> 4);
        if (row < M)
            *(short8*)(C + (size_t)row * ldc + n0 + (idx & 15) * 8) =
                *(const short8*)(smem + idx * 8);
    }
}

// ---------------------------------------------------------------------------
// Flash attention v7 (unchanged from round 8: 64-row q-tiles, grid 1152,
// K reg-prefetch -> LDS, counted vmcnt(3), 3 raw barriers, setprio)
// ---------------------------------------------------------------------------
__global__ __launch_bounds__(256) void attn_flash3(
    const BF16* __restrict__ Q, const BF16* __restrict__ K,
    const BF16* __restrict__ VT, BF16* __restrict__ O)
{
    constexpr int NQ = 729, HDk = 96, DM = 1152, LDV = 768;
    __shared__ __align__(16) BF16 Ks[64 * 104];
    __shared__ __align__(16) BF16 Vs[112 * 64];
    __shared__ __align__(16) BF16 Ps[4][16 * 64];

    const int id = blockIdx.x;
    const int xcd = id & 7, slot = id >> 3;        // slot 0..143
    const int hb = slot / 12, qt = slot - hb * 12; // hb 0..11, qt 0..11
    const int hg = xcd * 12 + hb;
    const int b = hg / 12, hh = hg - b * 12;

    const int tid = threadIdx.x, wave = tid >> 6, lane = tid & 63;
    const int quad = lane >> 4, l16 = lane & 15;
    const size_t kbase = (size_t)b * (NQ * DM) + (size_t)hh * (NQ * HDk);
    const size_t vbase = (size_t)hg * 112 * LDV;

    const short8 zero8 = {0, 0, 0, 0, 0, 0, 0, 0};
    const v4f zf = {0.f, 0.f, 0.f, 0.f};
    const float C2 = 0.14724445f;   // (1/sqrt(96)) * log2(e)

    const int q0w = qt * 64 + wave * 16;
    short8 aq[3];
    {
        int qrow = q0w + l16;
#pragma unroll
        for (int ks = 0; ks < 3; ++ks)
            aq[ks] = (qrow < NQ)
                ? *(const short8*)(Q + kbase + (size_t)qrow * HDk + ks * 32 + quad * 8)
                : zero8;
    }

    int kk_[3], kg_[3];
#pragma unroll
    for (int i = 0; i < 3; ++i) {
        int c = tid + i * 256;
        kk_[i] = c / 12; kg_[i] = c - kk_[i] * 12;
    }
    int vq_[4], vgr_[4], vhd_[4];
#pragma unroll
    for (int i = 0; i < 4; ++i) {
        int q = wave + 4 * i;
        vq_[i] = q;
        int hd = q * 8 + (lane >> 3);
        vhd_[i] = hd;
        vgr_[i] = ((lane & 7) - hd) & 7;
    }

    v4f oacc[7];
#pragma unroll
    for (int nt = 0; nt < 7; ++nt) oacc[nt] = zf;

    short8 kreg[3];
#pragma unroll
    for (int i = 0; i < 3; ++i)
        kreg[i] = *(const short8*)(K + kbase + (size_t)kk_[i] * HDk + kg_[i] * 8);

    for (int kt = 0; kt < 12; ++kt) {
        const int k0 = kt * 64;
#pragma unroll
        for (int i = 0; i < 3; ++i)
            *(short8*)(Ks + kk_[i] * 104 + kg_[i] * 8) = kreg[i];
#pragma unroll
        for (int i = 0; i < 4; ++i) {
            if (vq_[i] < 14)
                async_cp16(VT + vbase + (size_t)vhd_[i] * LDV + k0 + vgr_[i] * 8,
                           Vs + vq_[i] * 512);
        }
        asm volatile("s_waitcnt lgkmcnt(0)" ::: "memory");
        __builtin_amdgcn_s_barrier();
        __builtin_amdgcn_sched_barrier(0);
        {
            const int kn = (kt < 11) ? (k0 + 64) : 0;
#pragma unroll
            for (int i = 0; i < 3; ++i)
                kreg[i] = *(const short8*)(K + kbase + (size_t)(kn + kk_[i]) * HDk + kg_[i] * 8);
        }

        v4f s[4];
#pragma unroll
        for (int nt = 0; nt < 4; ++nt) s[nt] = zf;
        __builtin_amdgcn_s_setprio(1);
#pragma unroll
        for (int ks = 0; ks < 3; ++ks)
#pragma unroll
            for (int nt = 0; nt < 4; ++nt) {
                short8 bk = *(const short8*)(Ks + (nt * 16 + l16) * 104 + ks * 32 + quad * 8);
                s[nt] = __builtin_amdgcn_mfma_f32_16x16x32_bf16(aq[ks], bk, s[nt], 0, 0, 0);
            }
        __builtin_amdgcn_s_setprio(0);

        BF16* Pw = &Ps[wave][0];
#pragma unroll
        for (int nt = 0; nt < 4; ++nt)
#pragma unroll
            for (int r = 0; r < 4; ++r)
                Pw[((quad * 4 + r) << 6)
                   + ((((nt << 1) | (l16 >> 3)) ^ (quad << 1)) << 3)
                   + (l16 & 7)] =
                    __float2bfloat16(exp2f(s[nt][r] * C2));
        asm volatile("s_waitcnt lgkmcnt(0)" ::: "memory");

        short8 ap[2];
#pragma unroll
        for (int kc = 0; kc < 2; ++kc)
            ap[kc] = *(const short8*)(Pw + (l16 << 6)
                + ((((kc << 2) | quad) ^ (((l16 >> 2) & 3) << 1)) << 3));

        asm volatile("s_waitcnt vmcnt(3)" ::: "memory");
        __builtin_amdgcn_s_barrier();
        __builtin_amdgcn_sched_barrier(0);

        __builtin_amdgcn_s_setprio(1);
#pragma unroll
        for (int nt = 0; nt < 7; ++nt) {
            int hd = nt * 16 + l16;
#pragma unroll
            for (int kc = 0; kc < 2; ++kc) {
                short8 bv = *(const short8*)(Vs + hd * 64 + (((kc * 4 + quad) + hd & 7) & 7) * 8);
                oacc[nt] = __builtin_amdgcn_mfma_f32_16x16x32_bf16(ap[kc], bv, oacc[nt], 0, 0, 0);
            }
        }
        __builtin_amdgcn_s_setprio(0);
        asm volatile("s_waitcnt lgkmcnt(0)" ::: "memory");
        __builtin_amdgcn_s_barrier();
        __builtin_amdgcn_sched_barrier(0);
    }

    {
        const int qb = q0w + quad * 4;
#pragma unroll
        for (int r = 0; r < 4; ++r) {
            int q = qb + r;
            float lv = __shfl(oacc[6][r], quad << 4, 64);
            float inv = (lv > 0.f) ? 1.f / lv : 0.f;
            if (q >= NQ) continue;
#pragma unroll
            for (int nt = 0; nt < 6; ++nt)
                O[(size_t)b * (NQ * DM) + (size_t)q * DM + hh * HDk + nt * 16 + l16] =
                    __float2bfloat16(oacc[nt][r] * inv);
        }
    }
}

// ---------------------------------------------------------------------------
// LayerNorm fused kernels (192 threads, exp2-gelu — unchanged)
// ---------------------------------------------------------------------------
__device__ __forceinline__ float block_sum192(float v, float* red, int tid)
{
#pragma unroll
    for (int mm = 1; mm < 64; mm <<= 1) v += __shfl_xor(v, mm, 64);
    if ((tid & 63) == 0) red[tid >> 6] = v;
    __syncthreads();
    float r = red[0] + red[1] + red[2];
    __syncthreads();
    return r;
}

__global__ __launch_bounds__(192) void ln1_gelu_kernel(
    const BF16* __restrict__ ao, const float* __restrict__ x,
    const float* __restrict__ gw, const float* __restrict__ bw,
    BF16* __restrict__ hout, BF16* __restrict__ gout)
{
    __shared__ float red[3];
    const int row = blockIdx.x, tid = threadIdx.x;
    const bool act = tid < 144;                 // 144 * 8 = 1152
    float v[8];
    float s = 0.f;
    if (act) {
        short8 pk = ((const short8*)(ao + (size_t)row * 1152))[tid];
#pragma unroll
        for (int j = 0; j < 8; ++j) { v[j] = bs2f(pk[j]); s += v[j]; }
    } else {
#pragma unroll
        for (int j = 0; j < 8; ++j) v[j] = 0.f;
    }
    s = block_sum192(s, red, tid);
    float mu = s * (1.f / 1152.f);
    float vsum = 0.f;
    if (act) {
#pragma unroll
        for (int j = 0; j < 8; ++j) { float d = v[j] - mu; vsum += d * d; }
    }
    vsum = block_sum192(vsum, red, tid);
    float rstd = rsqrtf(vsum * (1.f / 1152.f) + 1e-6f);
    if (act) {
        f4 g0 = ((const f4*)gw)[2 * tid], g1 = ((const f4*)gw)[2 * tid + 1];
        f4 b0 = ((const f4*)bw)[2 * tid], b1 = ((const f4*)bw)[2 * tid + 1];
        const f4* xr = (const f4*)(x + (size_t)row * 1152);
        f4 x0 = xr[2 * tid], x1 = xr[2 * tid + 1];
        short8 ho, go;
#pragma unroll
        for (int j = 0; j < 8; ++j) {
            float gj = (j < 4) ? g0[j] : g1[j - 4];
            float bj = (j < 4) ? b0[j] : b1[j - 4];
            float xj = (j < 4) ? x0[j] : x1[j - 4];
            float hv = (v[j] - mu) * rstd * gj + bj + xj;
            ho[j] = f2bs(hv);
            float z2 = 2.3022077f * hv + 0.10294636f * hv * hv * hv;
            float gl = hv / (1.f + exp2f(-z2));
            go[j] = f2bs(gl);
        }
        ((short8*)(hout + (size_t)row * 1152))[tid] = ho;
        ((short8*)(gout + (size_t)row * 1152))[tid] = go;
    }
}

__global__ __launch_bounds__(192) void ln2_kernel(
    const BF16* __restrict__ m2, const BF16* __restrict__ hf,
    const float* __restrict__ gw, const float* __restrict__ bw,
    float* __restrict__ out)
{
    __shared__ float red[3];
    const int row = blockIdx.x, tid = threadIdx.x;
    const bool act = tid < 144;
    float v[8];
    float s = 0.f;
    if (act) {
        short8 pk = ((const short8*)(m2 + (size_t)row * 1152))[tid];
#pragma unroll
        for (int j = 0; j < 8; ++j) { v[j] = bs2f(pk[j]); s += v[j]; }
    } else {
#pragma unroll
        for (int j = 0; j < 8; ++j) v[j] = 0.f;
    }
    s = block_sum192(s, red, tid);
    float mu = s * (1.f / 1152.f);
    float vsum = 0.f;
    if (act) {
#pragma unroll
        for (int j = 0; j < 8; ++j) { float d = v[j] - mu; vsum += d * d; }
    }
    vsum = block_sum192(vsum, red, tid);
    float rstd = rsqrtf(vsum * (1.f / 1152.f) + 1e-6f);
    if (act) {
        f4 g0 = ((const f4*)gw)[2 * tid], g1 = ((const f4*)gw)[2 * tid + 1];
        f4 b0 = ((const f4*)bw)[2 * tid], b1 = ((const f4*)bw)[2 * tid + 1];
        short8 hfv = ((const short8*)(hf + (size_t)row * 1152))[tid];
        f4 o0, o1;
#pragma unroll
        for (int j = 0; j < 8; ++j) {
            float gj = (j < 4) ? g0[j] : g1[j - 4];
            float bj = (j < 4) ? b0[j] : b1[j - 4];
            float ov = (v[j] - mu) * rstd * gj + bj + bs2f(hfv[j]);
            if (j < 4) o0[j] = ov; else o1[j - 4] = ov;
        }
        f4* orow = (f4*)(out + (size_t)row * 1152);
        orow[2 * tid] = o0;
        orow[2 * tid + 1] = o1;
    }
}

// ---------------------------------------------------------------------------
// Workspace layout (~125 MB). Pws (fp32, 10.6 MB, z=2 planes) overlays S3
// during L2/L3 (S3 first written by attention in L4 — proven overlay, r3/r4).
// ---------------------------------------------------------------------------
extern "C" void kernel_launch(void* const* d_in, const int* in_sizes, int n_in,
                              void* d_out, int out_size, void* d_ws, size_t ws_size,
                              hipStream_t stream)
{
    const float* x    = (const float*)d_in[0];
    const float* wq   = (const float*)d_in[1];
    const float* bq   = (const float*)d_in[2];
    const float* wk   = (const float*)d_in[3];
    const float* bk   = (const float*)d_in[4];
    const float* wv   = (const float*)d_in[5];
    const float* bv   = (const float*)d_in[6];
    const float* wo   = (const float*)d_in[7];
    const float* bo   = (const float*)d_in[8];
    const float* ln1g = (const float*)d_in[9];
    const float* ln1b = (const float*)d_in[10];
    const float* wfc1 = (const float*)d_in[11];
    const float* bfc1 = (const float*)d_in[12];
    const float* wfc2 = (const float*)d_in[13];
    const float* bfc2 = (const float*)d_in[14];
    const float* ln2g = (const float*)d_in[15];
    const float* ln2b = (const float*)d_in[16];

    const int T = 8 * 729;           // 5832
    const int D = 1152, HIDP = 4352;
    const size_t TD = (size_t)T * D;
    const size_t WDD = (size_t)D * D;

    BF16* wbq   = (BF16*)d_ws;
    BF16* wbk   = wbq + WDD;
    BF16* wbv   = wbk + WDD;
    BF16* wbo   = wbv + WDD;
    BF16* wbf1t = wbo + WDD;                   // [1152][4352] (W1^T)
    BF16* wbf2  = wbf1t + (size_t)HIDP * D;    // [1152][4352]
    BF16* xb    = wbf2 + (size_t)D * HIDP;
    BF16* S0    = xb + TD;
    BF16* S1    = S0 + TD;
    BF16* S2    = S1 + TD;
    BF16* S3    = S2 + TD;
    BF16* C0    = S3 + TD;
    BF16* C1    = C0 + TD;
    BF16* VT    = C0;                          // [96*112*768] overlays C0+C1 head
    float* Pws  = (float*)S3;                  // [2][1152][1152] fp32 planes

    static float* bp_dev = nullptr;
    static BF16*  wm_dev = nullptr;
    if (!bp_dev) hipGetSymbolAddress((void**)&bp_dev, HIP_SYMBOL(g_bp));
    if (!wm_dev) hipGetSymbolAddress((void**)&wm_dev, HIP_SYMBOL(g_wm));

    dim3 blk(256);

    // L1: converts + W1^T + fused bias
    prep_kernel<<<18153, blk, 0, stream>>>(
        wq, wk, wv, wo, wfc1, wfc2, x, bfc1, bfc2,
        wbq, wbk, wbv, wbo, wbf1t, wbf2, xb);

    // L2: weight-merge split-K z=2 (first in dispatch order) || fused QKV
    qkv_wm8_kernel<<<484, dim3(512), 0, stream>>>(
        xb, wbq, bq, bk, bv, S0, TD, T, wbf2, wbf1t, Pws);

    // L3: V transpose + VT tail + Wm reduce
    trans_kernel<<<3024, blk, 0, stream>>>(S2, VT, Pws, wm_dev);

    // L4: attention (v7: 64-row q-tiles, grid 1152)
    attn_flash3<<<1152, blk, 0, stream>>>(S0, S1, VT, S3);

    // L5: output projection (TM=64, 828 blocks — r9 proved TLP > one-round)
    gemm_bt_t<64><<<828, blk, 0, stream>>>(S3, D, wbo, D, bo, D, C0, D, T, D, 9);

    // L6: LN1 + residual + gelu (192 threads)
    ln1_gelu_kernel<<<T, dim3(192), 0, stream>>>(C0, x, ln1g, ln1b, C1, C0);

    // L7: merged-MLP apply (TM=64)
    gemm_bt_t<64><<<828, blk, 0, stream>>>(C0, D, wm_dev, D, bp_dev, D, S3, D, T, D, 9);

    // L8: LN2 + residual -> d_out (fp32, 192 threads)
    ln2_kernel<<<T, dim3(192), 0, stream>>>(S3, C1, ln2g, ln2b, (float*)d_out);
}